// Round 10
// baseline (26.985 us; speedup 1.0000x reference)
//
#include <hip/hip_runtime.h>

#define B 32
#define R 48
#define L 128
#define D 64

// ---------------- fused single-dispatch kernel ----------------
// grid = (R/2)*(B/2) = 384 blocks; block = 1024 threads = 16 waves.
// Block tile: 2 r x 2 b, FULL L. Wave w handles l in [8w, 8w+8) for all
// 4 (r,b) pairs (acc[2][2] per lane, lane = d). 14 streams x 2KB per wave.
// Epilogue: LDS reduce over 16 waves + bias + relu + store. No workspace.
__global__ __launch_bounds__(1024) void alnn_fused(
    const float* __restrict__ X, const float* __restrict__ T,
    const float* __restrict__ M, const float* __restrict__ PD,
    const float* __restrict__ alpha, const float* __restrict__ w_v,
    const float* __restrict__ w_t, const float* __restrict__ b_t,
    const float* __restrict__ b_v, const float* __restrict__ ref_time,
    float* __restrict__ out)
{
    const int bt = blockIdx.x & 15;       // 0..15  (b-tile)
    const int rt = blockIdx.x >> 4;       // 0..23  (r-tile)
    const int d  = threadIdx.x & 63;
    const int w  = threadIdx.x >> 6;      // wave 0..15
    const int r0 = rt * 2, b0 = bt * 2;

    float a_[2], rt_[2];
    #pragma unroll
    for (int r = 0; r < 2; ++r) {
        a_[r]  = fmaxf(alpha[r0 + r], 0.0f);
        rt_[r] = ref_time[r0 + r];
    }

    float acc[2][2] = {{0.0f, 0.0f}, {0.0f, 0.0f}};

    const float4* __restrict__ w_t4 = reinterpret_cast<const float4*>(w_t);
    const int l0 = w * 8;                 // 8 l's per wave

    #pragma unroll 2
    for (int li = 0; li < 8; ++li) {
        const int l = l0 + li;
        float4 wt[2]; float btv[2], wv[2];
        #pragma unroll
        for (int r = 0; r < 2; ++r) {
            const int iw = ((r0 + r) * L + l) * D + d;
            wt[r]  = w_t4[iw];
            btv[r] = 4.0f * b_t[iw];
            wv[r]  = w_v[iw];
        }
        float xv[2], tv[2], mv[2], pv[2];
        #pragma unroll
        for (int b = 0; b < 2; ++b) {
            const int ix = ((b0 + b) * L + l) * D + d;
            xv[b] = X[ix];  tv[b] = T[ix];  mv[b] = M[ix];  pv[b] = PD[ix];
        }
        #pragma unroll
        for (int r = 0; r < 2; ++r) {
            #pragma unroll
            for (int b = 0; b < 2; ++b) {
                const float dist  = fabsf(tv[b] - rt_[r]);
                const float kern  = __expf(-a_[r] * dist);
                const float inten = fmaxf(xv[b] * kern, 0.0f);
                const float ssum  = fmaf(wt[r].x, xv[b],
                                    fmaf(wt[r].y, inten,
                                    fmaf(wt[r].z, mv[b],
                                    fmaf(wt[r].w, pv[b], btv[r]))));
                acc[r][b] = fmaf(wv[r], fmaxf(ssum, 0.0f), acc[r][b]);
            }
        }
    }

    // LDS reduce across the 16 waves. red[w][p][d]: writes are consecutive-d
    // per instruction (conflict-free); final reads are consecutive-d too.
    __shared__ float red[16][4][64];
    #pragma unroll
    for (int r = 0; r < 2; ++r)
        #pragma unroll
        for (int b = 0; b < 2; ++b)
            red[w][r * 2 + b][d] = acc[r][b];
    __syncthreads();

    if (threadIdx.x < 256) {
        const int p  = threadIdx.x >> 6;  // 0..3 -> (r,b)
        const int r  = p >> 1, b = p & 1;
        float sum = 0.0f;
        #pragma unroll
        for (int k = 0; k < 16; ++k)
            sum += red[k][p][d];
        const float o = fmaxf(sum + (float)L * b_v[(r0 + r) * D + d], 0.0f);
        out[((b0 + b) * R + (r0 + r)) * D + d] = o;
    }
}

extern "C" void kernel_launch(void* const* d_in, const int* in_sizes, int n_in,
                              void* d_out, int out_size, void* d_ws, size_t ws_size,
                              hipStream_t stream) {
    const float* X  = (const float*)d_in[0];
    const float* T  = (const float*)d_in[1];
    const float* M  = (const float*)d_in[2];
    const float* PD = (const float*)d_in[3];
    const float* alpha = (const float*)d_in[4];
    const float* w_v   = (const float*)d_in[5];
    const float* w_t   = (const float*)d_in[6];
    const float* b_t   = (const float*)d_in[7];
    const float* b_v   = (const float*)d_in[8];
    const float* ref_time = (const float*)d_in[9];
    float* out = (float*)d_out;

    hipLaunchKernelGGL(alnn_fused, dim3((R / 2) * (B / 2)), dim3(1024), 0, stream,
                       X, T, M, PD, alpha, w_v, w_t, b_t, b_v, ref_time, out);
}

// Round 11
// 16.766 us; speedup vs baseline: 1.6095x; 1.6095x over previous
//
#include <hip/hip_runtime.h>

#define B 32
#define R 48
#define L 128
#define D 64

// ---------------- tiled partial kernel, templated on tile/split ----------------
// grid = (R/TR_)*(B/TB_)*NS_, block = 256 (4 waves; lane = d).
// Each wave handles LW = L/NS_/4 l-values for all TR_*TB_ (r,b) pairs.
template<int TR_, int TB_, int NS_>
__global__ __launch_bounds__(256) void alnn_part1_t(
    const float* __restrict__ X, const float* __restrict__ T,
    const float* __restrict__ M, const float* __restrict__ PD,
    const float* __restrict__ alpha, const float* __restrict__ w_v,
    const float* __restrict__ w_t, const float* __restrict__ b_t,
    const float* __restrict__ ref_time, float* __restrict__ ws)
{
    constexpr int NBT = B / TB_;
    constexpr int LCH = L / NS_;
    constexpr int LW  = LCH / 4;          // l-values per wave
    const int id   = blockIdx.x;
    const int s    = id % NS_;
    const int rest = id / NS_;
    const int bt   = rest % NBT;
    const int rt   = rest / NBT;
    const int d    = threadIdx.x & 63;
    const int ly   = threadIdx.x >> 6;    // wave 0..3
    const int r0 = rt * TR_, b0 = bt * TB_;

    float a_[TR_], rt_[TR_];
    #pragma unroll
    for (int r = 0; r < TR_; ++r) {
        a_[r]  = fmaxf(alpha[r0 + r], 0.0f);
        rt_[r] = ref_time[r0 + r];
    }

    float acc[TR_][TB_];
    #pragma unroll
    for (int r = 0; r < TR_; ++r)
        #pragma unroll
        for (int b = 0; b < TB_; ++b) acc[r][b] = 0.0f;

    const float4* __restrict__ w_t4 = reinterpret_cast<const float4*>(w_t);
    const int l0 = s * LCH + ly * LW;

    #pragma unroll
    for (int li = 0; li < LW; ++li) {
        const int l = l0 + li;
        float4 wt[TR_]; float btv[TR_], wv[TR_];
        #pragma unroll
        for (int r = 0; r < TR_; ++r) {
            const int iw = ((r0 + r) * L + l) * D + d;
            wt[r]  = w_t4[iw];
            btv[r] = 4.0f * b_t[iw];
            wv[r]  = w_v[iw];
        }
        float xv[TB_], tv[TB_], mv[TB_], pv[TB_];
        #pragma unroll
        for (int b = 0; b < TB_; ++b) {
            const int ix = ((b0 + b) * L + l) * D + d;
            xv[b] = X[ix];  tv[b] = T[ix];  mv[b] = M[ix];  pv[b] = PD[ix];
        }
        #pragma unroll
        for (int r = 0; r < TR_; ++r) {
            #pragma unroll
            for (int b = 0; b < TB_; ++b) {
                const float dist  = fabsf(tv[b] - rt_[r]);
                const float kern  = __expf(-a_[r] * dist);
                const float inten = fmaxf(xv[b] * kern, 0.0f);
                const float ssum  = fmaf(wt[r].x, xv[b],
                                    fmaf(wt[r].y, inten,
                                    fmaf(wt[r].z, mv[b],
                                    fmaf(wt[r].w, pv[b], btv[r]))));
                acc[r][b] = fmaf(wv[r], fmaxf(ssum, 0.0f), acc[r][b]);
            }
        }
    }

    __shared__ float red[4][TR_ * TB_][64];
    #pragma unroll
    for (int r = 0; r < TR_; ++r)
        #pragma unroll
        for (int b = 0; b < TB_; ++b)
            red[ly][r * TB_ + b][d] = acc[r][b];
    __syncthreads();

    #pragma unroll
    for (int p = ly; p < TR_ * TB_; p += 4) {
        const int r = p / TB_, b = p % TB_;
        const float v = red[0][p][d] + red[1][p][d] + red[2][p][d] + red[3][p][d];
        ws[(((size_t)s * B + (b0 + b)) * R + (r0 + r)) * D + d] = v;
    }
}

// ---------------- finalize: sum NS_ partials + bias + relu ----------------
template<int NS_>
__global__ __launch_bounds__(256) void alnn_part2_t(
    const float* __restrict__ ws, const float* __restrict__ b_v,
    float* __restrict__ out)
{
    const int i = blockIdx.x * 256 + threadIdx.x;   // i = (b*R + r)*D + d
    const int d = i & 63;
    const int r = (i >> 6) % R;
    const int b = i / (R * D);
    float sum = 0.0f;
    #pragma unroll
    for (int s = 0; s < NS_; ++s)
        sum += ws[(((size_t)s * B + b) * R + r) * D + d];
    out[i] = fmaxf(sum + (float)L * b_v[r * D + d], 0.0f);
}

// ---------------- fallback (round-1 kernel) if ws too small ----------------
__global__ __launch_bounds__(256) void alnn_fallback(
    const float* __restrict__ X, const float* __restrict__ T,
    const float* __restrict__ M, const float* __restrict__ PD,
    const float* __restrict__ alpha, const float* __restrict__ w_v,
    const float* __restrict__ w_t, const float* __restrict__ b_t,
    const float* __restrict__ b_v, const float* __restrict__ ref_time,
    float* __restrict__ out)
{
    const int br = blockIdx.x;
    const int b  = br / R;
    const int r  = br - b * R;
    const int d  = threadIdx.x & 63;
    const int ly = threadIdx.x >> 6;

    const float a  = fmaxf(alpha[r], 0.0f);
    const float rt = ref_time[r];
    const int baseX = b * L * D + d;
    const int baseW = r * L * D + d;

    float acc = 0.0f;
    const int l0 = ly * 32;
    #pragma unroll 4
    for (int li = 0; li < 32; ++li) {
        const int l  = l0 + li;
        const int ix = baseX + l * D;
        const int iw = baseW + l * D;
        const float x  = X[ix], t = T[ix], m = M[ix], pd = PD[ix];
        const float dist  = fabsf(t - rt);
        const float kern  = __expf(-a * dist);
        const float inten = fmaxf(x * kern, 0.0f);
        const float4 wt = reinterpret_cast<const float4*>(w_t)[iw];
        const float bt  = b_t[iw];
        float s = fmaf(wt.x, x, fmaf(wt.y, inten, fmaf(wt.z, m, fmaf(wt.w, pd, 4.0f * bt))));
        acc = fmaf(w_v[iw], fmaxf(s, 0.0f), acc);
    }
    __shared__ float red[4][64];
    red[ly][d] = acc;
    __syncthreads();
    if (ly == 0) {
        const float sum = red[0][d] + red[1][d] + red[2][d] + red[3][d];
        out[(b * R + r) * D + d] = fmaxf(sum + (float)L * b_v[r * D + d], 0.0f);
    }
}

extern "C" void kernel_launch(void* const* d_in, const int* in_sizes, int n_in,
                              void* d_out, int out_size, void* d_ws, size_t ws_size,
                              hipStream_t stream) {
    const float* X  = (const float*)d_in[0];
    const float* T  = (const float*)d_in[1];
    const float* M  = (const float*)d_in[2];
    const float* PD = (const float*)d_in[3];
    const float* alpha = (const float*)d_in[4];
    const float* w_v   = (const float*)d_in[5];
    const float* w_t   = (const float*)d_in[6];
    const float* b_t   = (const float*)d_in[7];
    const float* b_v   = (const float*)d_in[8];
    const float* ref_time = (const float*)d_in[9];
    float* out = (float*)d_out;
    float* ws  = (float*)d_ws;

    const size_t ws16 = (size_t)16 * B * R * D * sizeof(float);  // 6.29 MB
    const size_t ws4  = (size_t) 4 * B * R * D * sizeof(float);  // 1.57 MB

    if (ws_size >= ws16) {
        // TR=4,TB=4,NS=16: 12*8*16 = 1536 blocks, 10 B/point  (R3 champion)
        hipLaunchKernelGGL((alnn_part1_t<4, 4, 16>), dim3(1536), dim3(256), 0, stream,
                           X, T, M, PD, alpha, w_v, w_t, b_t, ref_time, ws);
        hipLaunchKernelGGL((alnn_part2_t<16>), dim3(B * R * D / 256), dim3(256), 0, stream,
                           ws, b_v, out);
    } else if (ws_size >= ws4) {
        // TR=2,TB=2,NS=4: 24*16*4 = 1536 blocks, 20 B/point
        hipLaunchKernelGGL((alnn_part1_t<2, 2, 4>), dim3(1536), dim3(256), 0, stream,
                           X, T, M, PD, alpha, w_v, w_t, b_t, ref_time, ws);
        hipLaunchKernelGGL((alnn_part2_t<4>), dim3(B * R * D / 256), dim3(256), 0, stream,
                           ws, b_v, out);
    } else {
        hipLaunchKernelGGL(alnn_fallback, dim3(B * R), dim3(256), 0, stream,
                           X, T, M, PD, alpha, w_v, w_t, b_t, b_v, ref_time, out);
    }
}